// Round 2
// baseline (55.939 us; speedup 1.0000x reference)
//
#include <hip/hip_runtime.h>

// Output layout (flat float32, reference return order):
//   out0: voxel_features  [N, 4]
//   out1: voxel_coords    [N, 4]   (int values written as float)
//   out2: patch_center_xyz[V, 3]
//   out3: patch_num_list  [B]      (int values written as float)
//
// Single fused kernel. Each 256-thread block:
//   - recomputes the inclusive cumsum of the P patch counts in LDS
//     (8 KiB, L2-resident after the first blocks -> ~zero extra HBM)
//   - handles 32 voxels: 8 lanes/voxel mean-pool + coords binary search
//   - block 0 additionally writes centers z-pad and num_list

#define P_MAX 4096  // LDS capacity guard for the scan (P=2048 in practice)

__global__ __launch_bounds__(256) void fused_kernel(
    const float4* __restrict__ pv,    // [N*32] float4  (N,32,4)
    const int*    __restrict__ npts,  // [N]
    const int4*   __restrict__ coords,// [N]
    const int*    __restrict__ counts,// [P]
    const float*  __restrict__ centers,// [V,2]
    const int*    __restrict__ nums,  // [B]
    float4* __restrict__ out0,        // [N] features
    float4* __restrict__ out1,        // [N] coords-as-float
    float*  __restrict__ out2,        // [V,3]
    float*  __restrict__ out3,        // [B]
    int n_voxels, int P, int V, int B)
{
    __shared__ int s_accu[P_MAX];
    __shared__ int s_part[256];

    const int tid   = threadIdx.x;
    const int voxel = blockIdx.x * 32 + (tid >> 3);
    const int t     = tid & 7;

    // ---- issue the big global loads FIRST so they overlap the scan ----
    float4 v0, v1, v2, v3;
    int4 c;
    int np = 0;
    const bool active = (voxel < n_voxels);
    if (active) {
        const float4* base = pv + (size_t)voxel * 32;
        v0 = base[t + 0];
        v1 = base[t + 8];
        v2 = base[t + 16];
        v3 = base[t + 24];
        if (t == 0) { np = npts[voxel]; }
        if (t == 1) { c = coords[voxel]; }
    }

    // ---- block-local inclusive scan of counts into s_accu ----
    {
        const int chunk = (P + 255) >> 8;          // counts per thread
        const int beg = tid * chunk;
        const int end = min(beg + chunk, P);
        int s = 0;
        for (int i = beg; i < end; ++i) s += counts[i];
        s_part[tid] = s;
        __syncthreads();
        for (int off = 1; off < 256; off <<= 1) {
            int u = (tid >= off) ? s_part[tid - off] : 0;
            __syncthreads();
            s_part[tid] += u;
            __syncthreads();
        }
        int run = (tid == 0) ? 0 : s_part[tid - 1];
        for (int i = beg; i < end; ++i) {
            run += counts[i];                       // L2-hit re-read
            s_accu[i] = run;
        }
        __syncthreads();
    }

    if (active) {
        // ---- mean pooling: per-lane partial then 8-lane shuffle reduce ----
        float sx = v0.x + v1.x + v2.x + v3.x;
        float sy = v0.y + v1.y + v2.y + v3.y;
        float sz = v0.z + v1.z + v2.z + v3.z;
        float sw = v0.w + v1.w + v2.w + v3.w;
#pragma unroll
        for (int m = 4; m; m >>= 1) {
            sx += __shfl_xor(sx, m);
            sy += __shfl_xor(sy, m);
            sz += __shfl_xor(sz, m);
            sw += __shfl_xor(sw, m);
        }
        if (t == 0) {
            float inv = 1.0f / fmaxf((float)np, 1.0f);
            out0[voxel] = make_float4(sx * inv, sy * inv, sz * inv, sw * inv);
        }
        // ---- coords: searchsorted(accu, j, side='right') ----
        if (t == 1) {
            int lo = 0, hi = P;
            while (lo < hi) {
                int mid = (lo + hi) >> 1;
                if (s_accu[mid] <= voxel) lo = mid + 1; else hi = mid;
            }
            out1[voxel] = make_float4((float)lo, (float)c.y, (float)c.z, (float)c.w);
        }
    }

    // ---- tiny outputs: block 0 only ----
    if (blockIdx.x == 0) {
        for (int i = tid; i < V; i += 256) {
            out2[3 * i + 0] = centers[2 * i + 0];
            out2[3 * i + 1] = centers[2 * i + 1];
            out2[3 * i + 2] = 0.0f;
        }
        for (int i = tid; i < B; i += 256) out3[i] = (float)nums[i];
    }
}

extern "C" void kernel_launch(void* const* d_in, const int* in_sizes, int n_in,
                              void* d_out, int out_size, void* d_ws, size_t ws_size,
                              hipStream_t stream) {
    const float* pv      = (const float*)d_in[0];  // [N,32,4]
    const int*   npts    = (const int*)d_in[1];    // [N]
    const int*   coords  = (const int*)d_in[2];    // [N,4]
    const int*   pcounts = (const int*)d_in[3];    // [P]
    const float* centers = (const float*)d_in[4];  // [V,2]
    const int*   vnums   = (const int*)d_in[5];    // [B]

    const int N = in_sizes[1];       // 262144 voxels
    const int P = in_sizes[3];       // 2048 patches
    const int V = in_sizes[4] / 2;   // 2048 centers
    const int B = in_sizes[5];       // 4

    float* out0 = (float*)d_out;
    float* out1 = out0 + (size_t)N * 4;
    float* out2 = out1 + (size_t)N * 4;
    float* out3 = out2 + (size_t)V * 3;

    const int blocks = (N + 31) / 32;  // 32 voxels per 256-thread block
    fused_kernel<<<blocks, 256, 0, stream>>>(
        (const float4*)pv, npts, (const int4*)coords, pcounts, centers, vnums,
        (float4*)out0, (float4*)out1, out2, out3, N, P, V, B);
}

// Round 3
// 38.700 us; speedup vs baseline: 1.4455x; 1.4455x over previous
//
#include <hip/hip_runtime.h>

// Output layout (flat float32, reference return order):
//   out0: voxel_features  [N, 4]
//   out1: voxel_coords    [N, 4]   (int values written as float)
//   out2: patch_center_xyz[V, 3]
//   out3: patch_num_list  [B]      (int values written as float)

// ---------------------------------------------------------------------------
// Kernel A (tiny, 1 block): inclusive cumsum of patch counts -> ws,
// plus center z-pad and num-list passthrough.
// ---------------------------------------------------------------------------
__global__ __launch_bounds__(256) void scan_small_kernel(
    const int* __restrict__ counts, int P,
    const float* __restrict__ centers, int V,
    const int* __restrict__ nums, int B,
    int* __restrict__ accu,          // ws: inclusive cumsum [P]
    float* __restrict__ out2,        // [V,3]
    float* __restrict__ out3)        // [B]
{
    __shared__ int part[256];
    const int tid = threadIdx.x;
    const int chunk = (P + 255) / 256;
    const int beg = tid * chunk;
    const int end = min(beg + chunk, P);

    int s = 0;
    for (int i = beg; i < end; ++i) s += counts[i];
    part[tid] = s;
    __syncthreads();
    for (int off = 1; off < 256; off <<= 1) {
        int v = (tid >= off) ? part[tid - off] : 0;
        __syncthreads();
        part[tid] += v;
        __syncthreads();
    }
    int run = (tid == 0) ? 0 : part[tid - 1];
    for (int i = beg; i < end; ++i) {
        run += counts[i];
        accu[i] = run;
    }

    for (int i = tid; i < V; i += 256) {
        out2[3 * i + 0] = centers[2 * i + 0];
        out2[3 * i + 1] = centers[2 * i + 1];
        out2[3 * i + 2] = 0.0f;
    }
    for (int i = tid; i < B; i += 256) out3[i] = (float)nums[i];
}

// ---------------------------------------------------------------------------
// Kernel B: fused mean-pool + coords. 8 lanes/voxel, no LDS, no barriers.
// Coords lane (t==1) binary-searches the global accu (L2-resident; top
// levels broadcast from L1).
// ---------------------------------------------------------------------------
__global__ __launch_bounds__(256) void fused_main_kernel(
    const float4* __restrict__ pv,    // [N*32] float4  (N,32,4)
    const int*    __restrict__ npts,  // [N]
    const int4*   __restrict__ coords,// [N]
    const int*    __restrict__ accu,  // [P] inclusive cumsum
    float4* __restrict__ out0,        // [N] features
    float4* __restrict__ out1,        // [N] coords-as-float
    int n_voxels, int P)
{
    const int tid   = threadIdx.x;
    const int voxel = blockIdx.x * 32 + (tid >> 3);
    const int t     = tid & 7;
    if (voxel >= n_voxels) return;

    const float4* base = pv + (size_t)voxel * 32;
    float4 v0 = base[t + 0];
    float4 v1 = base[t + 8];
    float4 v2 = base[t + 16];
    float4 v3 = base[t + 24];

    // scalar side loads on dedicated lanes, overlapping the float4 loads
    int np = 0;
    int4 c;
    if (t == 0) np = npts[voxel];
    if (t == 1) c = coords[voxel];

    float sx = v0.x + v1.x + v2.x + v3.x;
    float sy = v0.y + v1.y + v2.y + v3.y;
    float sz = v0.z + v1.z + v2.z + v3.z;
    float sw = v0.w + v1.w + v2.w + v3.w;
#pragma unroll
    for (int m = 4; m; m >>= 1) {
        sx += __shfl_xor(sx, m);
        sy += __shfl_xor(sy, m);
        sz += __shfl_xor(sz, m);
        sw += __shfl_xor(sw, m);
    }
    if (t == 0) {
        float inv = 1.0f / fmaxf((float)np, 1.0f);
        out0[voxel] = make_float4(sx * inv, sy * inv, sz * inv, sw * inv);
    }
    if (t == 1) {
        int lo = 0, hi = P;
        while (lo < hi) {
            int mid = (lo + hi) >> 1;
            if (accu[mid] <= voxel) lo = mid + 1; else hi = mid;
        }
        out1[voxel] = make_float4((float)lo, (float)c.y, (float)c.z, (float)c.w);
    }
}

extern "C" void kernel_launch(void* const* d_in, const int* in_sizes, int n_in,
                              void* d_out, int out_size, void* d_ws, size_t ws_size,
                              hipStream_t stream) {
    const float* pv      = (const float*)d_in[0];  // [N,32,4]
    const int*   npts    = (const int*)d_in[1];    // [N]
    const int*   coords  = (const int*)d_in[2];    // [N,4]
    const int*   pcounts = (const int*)d_in[3];    // [P]
    const float* centers = (const float*)d_in[4];  // [V,2]
    const int*   vnums   = (const int*)d_in[5];    // [B]

    const int N = in_sizes[1];       // 262144 voxels
    const int P = in_sizes[3];       // 2048 patches
    const int V = in_sizes[4] / 2;   // 2048 centers
    const int B = in_sizes[5];       // 4

    float* out0 = (float*)d_out;
    float* out1 = out0 + (size_t)N * 4;
    float* out2 = out1 + (size_t)N * 4;
    float* out3 = out2 + (size_t)V * 3;
    int*   accu = (int*)d_ws;        // P ints

    scan_small_kernel<<<1, 256, 0, stream>>>(pcounts, P, centers, V, vnums, B,
                                             accu, out2, out3);

    const int blocks = (N + 31) / 32;  // 32 voxels per 256-thread block
    fused_main_kernel<<<blocks, 256, 0, stream>>>(
        (const float4*)pv, npts, (const int4*)coords, accu,
        (float4*)out0, (float4*)out1, N, P);
}

// Round 4
// 38.617 us; speedup vs baseline: 1.4486x; 1.0021x over previous
//
#include <hip/hip_runtime.h>

// Output layout (flat float32, reference return order):
//   out0: voxel_features  [N, 4]
//   out1: voxel_coords    [N, 4]   (int values written as float)
//   out2: patch_center_xyz[V, 3]
//   out3: patch_num_list  [B]      (int values written as float)

// ---------------------------------------------------------------------------
// Kernel A (tiny, 1 block, barrier-free): wave 0 scans the P patch counts
// via shuffle; waves 1-3 concurrently write centers z-pad and num_list.
// ---------------------------------------------------------------------------
__global__ __launch_bounds__(256) void scan_small_kernel(
    const int* __restrict__ counts, int P,
    const float* __restrict__ centers, int V,
    const int* __restrict__ nums, int B,
    int* __restrict__ accu,          // ws: inclusive cumsum [P]
    float* __restrict__ out2,        // [V,3]
    float* __restrict__ out3)        // [B]
{
    const int tid = threadIdx.x;
    if (tid < 64) {
        const int chunk = (P + 63) >> 6;
        const int beg = tid * chunk;
        const int end = min(beg + chunk, P);
        int s = 0;
        for (int i = beg; i < end; ++i) s += counts[i];
        // wave-inclusive scan of per-lane sums
        int acc = s;
#pragma unroll
        for (int off = 1; off < 64; off <<= 1) {
            int u = __shfl_up(acc, off);
            if (tid >= off) acc += u;
        }
        int run = acc - s;                      // exclusive prefix of this lane
        for (int i = beg; i < end; ++i) {
            run += counts[i];                   // L1-hot re-read
            accu[i] = run;
        }
    } else {
        const int t = tid - 64;                 // 192 threads
        for (int i = t; i < V; i += 192) {
            out2[3 * i + 0] = centers[2 * i + 0];
            out2[3 * i + 1] = centers[2 * i + 1];
            out2[3 * i + 2] = 0.0f;
        }
        for (int i = t; i < B; i += 192) out3[i] = (float)nums[i];
    }
}

// ---------------------------------------------------------------------------
// Kernel B: role-split blocks.
//   blocks [0, coordBlocks)          : coords (1 voxel/thread, binary search)
//   blocks [coordBlocks, ...)        : mean pooling (8 lanes/voxel, pure stream)
// Search-latency waves co-schedule with streaming waves on the same CUs
// instead of stretching every streaming wave's lifetime.
// ---------------------------------------------------------------------------
__global__ __launch_bounds__(256) void main_kernel(
    const float4* __restrict__ pv,     // [N*32] float4  (N,32,4)
    const int*    __restrict__ npts,   // [N]
    const int4*   __restrict__ coords, // [N]
    const int*    __restrict__ accu,   // [P] inclusive cumsum
    float4* __restrict__ out0,         // [N] features
    float4* __restrict__ out1,         // [N] coords-as-float
    int n_voxels, int P, int coordBlocks)
{
    const int b = blockIdx.x;
    if (b < coordBlocks) {
        const int j = b * 256 + threadIdx.x;
        if (j >= n_voxels) return;
        int4 c = coords[j];
        int lo = 0, hi = P;
        while (lo < hi) {
            int mid = (lo + hi) >> 1;
            if (accu[mid] <= j) lo = mid + 1; else hi = mid;
        }
        out1[j] = make_float4((float)lo, (float)c.y, (float)c.z, (float)c.w);
    } else {
        const int mb = b - coordBlocks;
        const int voxel = mb * 32 + (threadIdx.x >> 3);
        const int t = threadIdx.x & 7;
        if (voxel >= n_voxels) return;

        const float4* base = pv + (size_t)voxel * 32;
        float4 a0 = base[t + 0];
        float4 a1 = base[t + 8];
        float4 a2 = base[t + 16];
        float4 a3 = base[t + 24];
        int np = (t == 0) ? npts[voxel] : 0;

        float sx = a0.x + a1.x + a2.x + a3.x;
        float sy = a0.y + a1.y + a2.y + a3.y;
        float sz = a0.z + a1.z + a2.z + a3.z;
        float sw = a0.w + a1.w + a2.w + a3.w;
#pragma unroll
        for (int m = 4; m; m >>= 1) {
            sx += __shfl_xor(sx, m);
            sy += __shfl_xor(sy, m);
            sz += __shfl_xor(sz, m);
            sw += __shfl_xor(sw, m);
        }
        if (t == 0) {
            float inv = 1.0f / fmaxf((float)np, 1.0f);
            out0[voxel] = make_float4(sx * inv, sy * inv, sz * inv, sw * inv);
        }
    }
}

extern "C" void kernel_launch(void* const* d_in, const int* in_sizes, int n_in,
                              void* d_out, int out_size, void* d_ws, size_t ws_size,
                              hipStream_t stream) {
    const float* pv      = (const float*)d_in[0];  // [N,32,4]
    const int*   npts    = (const int*)d_in[1];    // [N]
    const int*   coords  = (const int*)d_in[2];    // [N,4]
    const int*   pcounts = (const int*)d_in[3];    // [P]
    const float* centers = (const float*)d_in[4];  // [V,2]
    const int*   vnums   = (const int*)d_in[5];    // [B]

    const int N = in_sizes[1];       // 262144 voxels
    const int P = in_sizes[3];       // 2048 patches
    const int V = in_sizes[4] / 2;   // 2048 centers
    const int B = in_sizes[5];       // 4

    float* out0 = (float*)d_out;
    float* out1 = out0 + (size_t)N * 4;
    float* out2 = out1 + (size_t)N * 4;
    float* out3 = out2 + (size_t)V * 3;
    int*   accu = (int*)d_ws;        // P ints

    scan_small_kernel<<<1, 256, 0, stream>>>(pcounts, P, centers, V, vnums, B,
                                             accu, out2, out3);

    const int coordBlocks = (N + 255) / 256;          // 1024
    const int meanBlocks  = (N + 31) / 32;            // 8192
    main_kernel<<<coordBlocks + meanBlocks, 256, 0, stream>>>(
        (const float4*)pv, npts, (const int4*)coords, accu,
        (float4*)out0, (float4*)out1, N, P, coordBlocks);
}

// Round 5
// 30.464 us; speedup vs baseline: 1.8363x; 1.2677x over previous
//
#include <hip/hip_runtime.h>

// Output layout (flat float32, reference return order):
//   out0: voxel_features  [N, 4]
//   out1: voxel_coords    [N, 4]   (int values written as float)
//   out2: patch_center_xyz[V, 3]
//   out3: patch_num_list  [B]      (int values written as float)
//
// SINGLE dispatch:
//   blocks [0, meanBlocks)                : mean pooling (8 lanes/voxel, stream)
//   blocks [meanBlocks, meanBlocks+cBlks) : coords by PATCH RANGE (no search) —
//       each block shuffle-scans the counts array in-block (L2-hot, 2 barriers)
//       then streams out1 rows for its patches' voxel range.
//   first coords block additionally writes centers z-pad + num_list.

#define P_MAX 4096   // LDS guard for in-block scan (P = 2048 in practice)

__global__ __launch_bounds__(256) void fused_all_kernel(
    const float4* __restrict__ pv,     // [N*32] float4  (N,32,4)
    const int*    __restrict__ npts,   // [N]
    const int4*   __restrict__ coords, // [N]
    const int*    __restrict__ counts, // [P]
    const float*  __restrict__ centers,// [V,2]
    const int*    __restrict__ nums,   // [B]
    float4* __restrict__ out0,         // [N] features
    float4* __restrict__ out1,         // [N] coords-as-float
    float*  __restrict__ out2,         // [V,3]
    float*  __restrict__ out3,         // [B]
    int n_voxels, int P, int V, int B,
    int meanBlocks, int ppb)           // ppb = patches per coords block
{
    __shared__ int s_accu[P_MAX];
    __shared__ int s_wsum[4];

    const int b = blockIdx.x;
    const int tid = threadIdx.x;

    if (b < meanBlocks) {
        // ---------------- mean pooling: pure stream ----------------
        const int voxel = b * 32 + (tid >> 3);
        const int t = tid & 7;
        if (voxel >= n_voxels) return;

        const float4* base = pv + (size_t)voxel * 32;
        float4 a0 = base[t + 0];
        float4 a1 = base[t + 8];
        float4 a2 = base[t + 16];
        float4 a3 = base[t + 24];
        int np = (t == 0) ? npts[voxel] : 0;

        float sx = a0.x + a1.x + a2.x + a3.x;
        float sy = a0.y + a1.y + a2.y + a3.y;
        float sz = a0.z + a1.z + a2.z + a3.z;
        float sw = a0.w + a1.w + a2.w + a3.w;
#pragma unroll
        for (int m = 4; m; m >>= 1) {
            sx += __shfl_xor(sx, m);
            sy += __shfl_xor(sy, m);
            sz += __shfl_xor(sz, m);
            sw += __shfl_xor(sw, m);
        }
        if (t == 0) {
            float inv = 1.0f / fmaxf((float)np, 1.0f);
            out0[voxel] = make_float4(sx * inv, sy * inv, sz * inv, sw * inv);
        }
        return;
    }

    // ---------------- coords by patch range ----------------
    const int cb = b - meanBlocks;

    // in-block inclusive scan of counts -> s_accu (shuffle + 2 barriers)
    {
        const int chunk = (P + 255) >> 8;
        const int cbeg = tid * chunk;
        const int cend = min(cbeg + chunk, P);
        int s = 0;
        for (int i = cbeg; i < cend; ++i) s += counts[i];

        const int lane = tid & 63;
        const int wave = tid >> 6;
        int acc = s;
#pragma unroll
        for (int off = 1; off < 64; off <<= 1) {
            int u = __shfl_up(acc, off);
            if (lane >= off) acc += u;
        }
        if (lane == 63) s_wsum[wave] = acc;
        __syncthreads();
        int wpre = 0;
        for (int w = 0; w < wave; ++w) wpre += s_wsum[w];
        int run = wpre + acc - s;              // exclusive prefix of this chunk
        for (int i = cbeg; i < cend; ++i) {
            run += counts[i];                  // L1-hot re-read
            s_accu[i] = run;
        }
        __syncthreads();
    }

    const int pBeg = cb * ppb;
    if (pBeg < P) {
        const int pEnd = min(pBeg + ppb, P);
        const int vBeg = (pBeg == 0) ? 0 : s_accu[pBeg - 1];
        const int vEnd = s_accu[pEnd - 1];

        for (int j = vBeg + tid; j < vEnd; j += 256) {
            // find patch: smallest k in [pBeg,pEnd) with s_accu[k] > j
            int p = pBeg;
            while (p < pEnd - 1 && s_accu[p] <= j) ++p;
            int4 c = coords[j];
            out1[j] = make_float4((float)p, (float)c.y, (float)c.z, (float)c.w);
        }
    }

    // tiny outputs on the first coords block
    if (cb == 0) {
        for (int i = tid; i < V; i += 256) {
            out2[3 * i + 0] = centers[2 * i + 0];
            out2[3 * i + 1] = centers[2 * i + 1];
            out2[3 * i + 2] = 0.0f;
        }
        for (int i = tid; i < B; i += 256) out3[i] = (float)nums[i];
    }
}

extern "C" void kernel_launch(void* const* d_in, const int* in_sizes, int n_in,
                              void* d_out, int out_size, void* d_ws, size_t ws_size,
                              hipStream_t stream) {
    const float* pv      = (const float*)d_in[0];  // [N,32,4]
    const int*   npts    = (const int*)d_in[1];    // [N]
    const int*   coords  = (const int*)d_in[2];    // [N,4]
    const int*   pcounts = (const int*)d_in[3];    // [P]
    const float* centers = (const float*)d_in[4];  // [V,2]
    const int*   vnums   = (const int*)d_in[5];    // [B]

    const int N = in_sizes[1];       // 262144 voxels
    const int P = in_sizes[3];       // 2048 patches
    const int V = in_sizes[4] / 2;   // 2048 centers
    const int B = in_sizes[5];       // 4

    float* out0 = (float*)d_out;
    float* out1 = out0 + (size_t)N * 4;
    float* out2 = out1 + (size_t)N * 4;
    float* out3 = out2 + (size_t)V * 3;

    const int meanBlocks  = (N + 31) / 32;               // 8192
    const int coordBlocks = 512;
    const int ppb         = (P + coordBlocks - 1) / coordBlocks;  // 4

    fused_all_kernel<<<meanBlocks + coordBlocks, 256, 0, stream>>>(
        (const float4*)pv, npts, (const int4*)coords, pcounts, centers, vnums,
        (float4*)out0, (float4*)out1, out2, out3,
        N, P, V, B, meanBlocks, ppb);
}

// Round 6
// 29.370 us; speedup vs baseline: 1.9046x; 1.0372x over previous
//
#include <hip/hip_runtime.h>

// Output layout (flat float32, reference return order):
//   out0: voxel_features  [N, 4]
//   out1: voxel_coords    [N, 4]   (int values written as float)
//   out2: patch_center_xyz[V, 3]
//   out3: patch_num_list  [B]      (int values written as float)
//
// SINGLE dispatch; coords blocks INTERLEAVED (every `stride`-th block) so
// their in-block scan + scatter overlaps the pv streaming instead of
// forming a serialized tail generation.

#define P_MAX 4096   // LDS guard for in-block scan (P = 2048 in practice)

__global__ __launch_bounds__(256) void fused_all_kernel(
    const float4* __restrict__ pv,     // [N*32] float4  (N,32,4)
    const int*    __restrict__ npts,   // [N]
    const int4*   __restrict__ coords, // [N]
    const int*    __restrict__ counts, // [P]
    const float*  __restrict__ centers,// [V,2]
    const int*    __restrict__ nums,   // [B]
    float4* __restrict__ out0,         // [N] features
    float4* __restrict__ out1,         // [N] coords-as-float
    float*  __restrict__ out2,         // [V,3]
    float*  __restrict__ out3,         // [B]
    int n_voxels, int P, int V, int B,
    int coordBlocks, int stride, int ppb)
{
    __shared__ int s_accu[P_MAX];
    __shared__ int s_wsum[4];

    const int b = blockIdx.x;
    const int tid = threadIdx.x;

    const int k = b / stride;
    const bool isCoords = (b % stride == 0) && (k < coordBlocks);

    if (!isCoords) {
        // ---------------- mean pooling: pure stream ----------------
        // number of coords blocks with index < b:
        int nC = k + ((b % stride != 0) ? 1 : 0);
        if (nC > coordBlocks) nC = coordBlocks;
        const int mb = b - nC;

        const int voxel = mb * 32 + (tid >> 3);
        const int t = tid & 7;
        if (voxel >= n_voxels) return;

        const float4* base = pv + (size_t)voxel * 32;
        float4 a0 = base[t + 0];
        float4 a1 = base[t + 8];
        float4 a2 = base[t + 16];
        float4 a3 = base[t + 24];
        int np = (t == 0) ? npts[voxel] : 0;

        float sx = a0.x + a1.x + a2.x + a3.x;
        float sy = a0.y + a1.y + a2.y + a3.y;
        float sz = a0.z + a1.z + a2.z + a3.z;
        float sw = a0.w + a1.w + a2.w + a3.w;
#pragma unroll
        for (int m = 4; m; m >>= 1) {
            sx += __shfl_xor(sx, m);
            sy += __shfl_xor(sy, m);
            sz += __shfl_xor(sz, m);
            sw += __shfl_xor(sw, m);
        }
        if (t == 0) {
            float inv = 1.0f / fmaxf((float)np, 1.0f);
            out0[voxel] = make_float4(sx * inv, sy * inv, sz * inv, sw * inv);
        }
        return;
    }

    // ---------------- coords by patch range ----------------
    const int cb = k;

    // in-block inclusive scan of counts -> s_accu (shuffle + 2 barriers)
    {
        const int chunk = (P + 255) >> 8;
        const int cbeg = tid * chunk;
        const int cend = min(cbeg + chunk, P);
        int s = 0;
        for (int i = cbeg; i < cend; ++i) s += counts[i];

        const int lane = tid & 63;
        const int wave = tid >> 6;
        int acc = s;
#pragma unroll
        for (int off = 1; off < 64; off <<= 1) {
            int u = __shfl_up(acc, off);
            if (lane >= off) acc += u;
        }
        if (lane == 63) s_wsum[wave] = acc;
        __syncthreads();
        int wpre = 0;
        for (int w = 0; w < wave; ++w) wpre += s_wsum[w];
        int run = wpre + acc - s;              // exclusive prefix of this chunk
        for (int i = cbeg; i < cend; ++i) {
            run += counts[i];                  // L1-hot re-read
            s_accu[i] = run;
        }
        __syncthreads();
    }

    const int pBeg = cb * ppb;
    if (pBeg < P) {
        const int pEnd = min(pBeg + ppb, P);
        const int vBeg = (pBeg == 0) ? 0 : s_accu[pBeg - 1];
        const int vEnd = s_accu[pEnd - 1];

        for (int j = vBeg + tid; j < vEnd; j += 256) {
            // smallest p in [pBeg,pEnd) with s_accu[p] > j
            int p = pBeg;
            while (p < pEnd - 1 && s_accu[p] <= j) ++p;
            int4 c = coords[j];
            out1[j] = make_float4((float)p, (float)c.y, (float)c.z, (float)c.w);
        }
    }

    // tiny outputs on the first coords block
    if (cb == 0) {
        for (int i = tid; i < V; i += 256) {
            out2[3 * i + 0] = centers[2 * i + 0];
            out2[3 * i + 1] = centers[2 * i + 1];
            out2[3 * i + 2] = 0.0f;
        }
        for (int i = tid; i < B; i += 256) out3[i] = (float)nums[i];
    }
}

extern "C" void kernel_launch(void* const* d_in, const int* in_sizes, int n_in,
                              void* d_out, int out_size, void* d_ws, size_t ws_size,
                              hipStream_t stream) {
    const float* pv      = (const float*)d_in[0];  // [N,32,4]
    const int*   npts    = (const int*)d_in[1];    // [N]
    const int*   coords  = (const int*)d_in[2];    // [N,4]
    const int*   pcounts = (const int*)d_in[3];    // [P]
    const float* centers = (const float*)d_in[4];  // [V,2]
    const int*   vnums   = (const int*)d_in[5];    // [B]

    const int N = in_sizes[1];       // 262144 voxels
    const int P = in_sizes[3];       // 2048 patches
    const int V = in_sizes[4] / 2;   // 2048 centers
    const int B = in_sizes[5];       // 4

    float* out0 = (float*)d_out;
    float* out1 = out0 + (size_t)N * 4;
    float* out2 = out1 + (size_t)N * 4;
    float* out3 = out2 + (size_t)V * 3;

    const int meanBlocks  = (N + 31) / 32;                        // 8192
    const int coordBlocks = 512;
    const int ppb         = (P + coordBlocks - 1) / coordBlocks;  // 4
    const int total       = meanBlocks + coordBlocks;             // 8704
    int stride = total / coordBlocks;                             // 17
    if (stride < 1) stride = 1;

    fused_all_kernel<<<total, 256, 0, stream>>>(
        (const float4*)pv, npts, (const int4*)coords, pcounts, centers, vnums,
        (float4*)out0, (float4*)out1, out2, out3,
        N, P, V, B, coordBlocks, stride, ppb);
}